// Round 1
// baseline (426.091 us; speedup 1.0000x reference)
//
#include <hip/hip_runtime.h>
#include <math.h>

// Problem constants (from reference): B=4, S=8192, H=2048, K=4, fp32.
#define CB 4
#define CS 8192
#define CH 2048
#define CH4 (CH / 4)      // 512 float4 groups per row
#define TT 64             // timesteps per thread (halo overhead 3/64 ~ 4.7%)

// Use a true clang vector type so __builtin_nontemporal_load/store accept it.
typedef float f4 __attribute__((ext_vector_type(4)));

__device__ __forceinline__ float silu_fast(float v) {
    // v * sigmoid(v); v_rcp_f32 is ~1 ulp — avoids the full-precision
    // div_scale/div_fmas/div_fixup dependent chain (~10 VALU ops).
    return v * __builtin_amdgcn_rcpf(1.0f + __expf(-v));
}

__global__ __launch_bounds__(256) void dwconv_silu_kernel(
        const float* __restrict__ x,
        const float* __restrict__ w,
        float* __restrict__ y) {
    const int tid = blockIdx.x * 256 + threadIdx.x;
    const int h4 = tid & (CH4 - 1);          // consecutive lanes -> consecutive float4 in H: coalesced
    const int strip = tid >> 9;              // tid / 512
    const int b = strip >> 7;                // / (S/TT = 128)
    const int t0 = (strip & 127) * TT;

    const f4* __restrict__ xb = reinterpret_cast<const f4*>(x) + (size_t)b * CS * CH4 + h4;
    f4* __restrict__ yb = reinterpret_cast<f4*>(y) + (size_t)b * CS * CH4 + h4;

    // Weight rows for channels h = 4*h4 .. 4*h4+3. wr{c}.x..w = w[h, 0..3]
    const f4* __restrict__ wv = reinterpret_cast<const f4*>(w) + (size_t)h4 * 4;
    const f4 wr0 = wv[0];
    const f4 wr1 = wv[1];
    const f4 wr2 = wv[2];
    const f4 wr3 = wv[3];

    // Sliding window: x[t-3], x[t-2], x[t-1]. t0 is a multiple of TT, so
    // only t0 == 0 needs the zero pad (wave-uniform branch: strip bits are
    // uniform across the 64 lanes).
    f4 xm3 = 0.f, xm2 = 0.f, xm1 = 0.f;
    if (t0 != 0) {
        const f4* hp = xb + (size_t)(t0 - 3) * CH4;
        xm3 = __builtin_nontemporal_load(hp);
        xm2 = __builtin_nontemporal_load(hp + CH4);
        xm1 = __builtin_nontemporal_load(hp + 2 * CH4);
    }

    // Strength-reduced addressing: pointer increment instead of
    // (size_t)t * CH4 (kills the per-iteration v_mad_u64 chains).
    const f4* __restrict__ xp = xb + (size_t)t0 * CH4;
    f4* __restrict__ yp = yb + (size_t)t0 * CH4;

    #pragma unroll 8
    for (int i = 0; i < TT; ++i) {
        const f4 cur = __builtin_nontemporal_load(xp);

        f4 o;
        o.x = wr0.x * xm3.x + wr0.y * xm2.x + wr0.z * xm1.x + wr0.w * cur.x;
        o.y = wr1.x * xm3.y + wr1.y * xm2.y + wr1.z * xm1.y + wr1.w * cur.y;
        o.z = wr2.x * xm3.z + wr2.y * xm2.z + wr2.z * xm1.z + wr2.w * cur.z;
        o.w = wr3.x * xm3.w + wr3.y * xm2.w + wr3.z * xm1.w + wr3.w * cur.w;

        o.x = silu_fast(o.x);
        o.y = silu_fast(o.y);
        o.z = silu_fast(o.z);
        o.w = silu_fast(o.w);

        __builtin_nontemporal_store(o, yp);

        xm3 = xm2;
        xm2 = xm1;
        xm1 = cur;
        xp += CH4;
        yp += CH4;
    }
}

extern "C" void kernel_launch(void* const* d_in, const int* in_sizes, int n_in,
                              void* d_out, int out_size, void* d_ws, size_t ws_size,
                              hipStream_t stream) {
    const float* x = (const float*)d_in[0];   // (B, S, H) fp32
    const float* w = (const float*)d_in[1];   // (H, K) fp32
    float* y = (float*)d_out;                 // (B, S, H) fp32

    const int total_threads = CB * (CS / TT) * CH4;  // 4 * 128 * 512 = 262144
    dwconv_silu_kernel<<<total_threads / 256, 256, 0, stream>>>(x, w, y);
}